// Round 1
// 528.684 us; speedup vs baseline: 1.0275x; 1.0275x over previous
//
#include <hip/hip_runtime.h>

typedef short bf8 __attribute__((ext_vector_type(8)));   // 8 bf16 (4 VGPRs)
typedef float f4 __attribute__((ext_vector_type(4)));
typedef unsigned int u32;
typedef u32 u32x4 __attribute__((ext_vector_type(4)));
typedef u32 u32x2 __attribute__((ext_vector_type(2)));

#define TPB 256

__device__ __forceinline__ f4 mfma16(bf8 a, bf8 b, f4 c) {
    return __builtin_amdgcn_mfma_f32_16x16x32_bf16(a, b, c, 0, 0, 0);
}

__device__ __forceinline__ void split1(float x, u32& h, u32& l) {
    u32 xb = __float_as_uint(x);
    u32 hb = xb & 0xFFFF0000u;
    float lf = x - __uint_as_float(hb);
    h = hb >> 16;
    l = __float_as_uint(lf) >> 16;
}

__device__ __forceinline__ u32 bf16_rne(float x) {
    u32 u = __float_as_uint(x);
    return (u + 0x7FFFu + ((u >> 16) & 1u)) >> 16;
}

__device__ __forceinline__ void cvt_split8(const float* a, bf8& H, bf8& L) {
    u32 hd[4], ld[4];
#pragma unroll
    for (int i = 0; i < 4; ++i) {
        u32 h0, l0, h1, l1;
        split1(a[2*i],   h0, l0);
        split1(a[2*i+1], h1, l1);
        hd[i] = h0 | (h1 << 16);
        ld[i] = l0 | (l1 << 16);
    }
    u32x4 hv = {hd[0], hd[1], hd[2], hd[3]};
    u32x4 lv = {ld[0], ld[1], ld[2], ld[3]};
    H = __builtin_bit_cast(bf8, hv);
    L = __builtin_bit_cast(bf8, lv);
}

// ---------------- prep: build hi/lo frag dumps once into d_ws ----------------
// FT concat layout (K=128): [white(49) | 0(15) | black(49) | 0(15)]
//   mat0 (Ww, accw): c<49 -> Ww[n][c]; 64<=c<113 -> Ww[n][c-15]; else 0
//   mat1 (Wb, accb): c<49 -> Wb[n][c+49]; 64<=c<113 -> Wb[n][c-64]; else 0
// L0/L1 use the packed-act column permutation col(k') = (k'>>5)*32 + (k'&1)*16 + ((k'>>1)&15)
__global__ void nnue_prep(const float* __restrict__ Ww, const float* __restrict__ Wb,
                          const float* __restrict__ W0, const float* __restrict__ W1,
                          const float* __restrict__ W2, u32* __restrict__ ws)
{
    int T = blockIdx.x * 256 + threadIdx.x;
    if (T < 5632) {
        int pair = T >> 8, idx = T & 255;
        int kq = idx >> 6, n = (idx >> 2) & 15, dj = idx & 3;
        u32 hp = 0, lp = 0;
#pragma unroll
        for (int e = 0; e < 2; ++e) {
            int kk = kq * 8 + dj * 2 + e;
            float x = 0.f;
            if (pair < 16) {
                int ks = pair >> 2, mat = (pair >> 1) & 1, t = pair & 1;
                int c = ks * 32 + kk;
                if (mat == 0) {
                    if (c < 49)                 x = Ww[(t*16+n)*98 + c];
                    else if (c >= 64 && c < 113) x = Ww[(t*16+n)*98 + c - 15];
                } else {
                    if (c < 49)                 x = Wb[(t*16+n)*98 + c + 49];
                    else if (c >= 64 && c < 113) x = Wb[(t*16+n)*98 + c - 64];
                }
            } else if (pair < 20) {
                int ks = (pair - 16) >> 1, t = (pair - 16) & 1;
                int k2 = ks * 32 + kk;
                int col = (k2 >> 5) * 32 + (k2 & 1) * 16 + ((k2 >> 1) & 15);
                x = W0[(t*16+n)*64 + col];
            } else {
                int t = pair - 20;
                int col = (kk & 1) * 16 + ((kk >> 1) & 15);
                x = W1[(t*16+n)*32 + col];
            }
            u32 h, l; split1(x, h, l);
            hp |= h << (16 * e);
            lp |= l << (16 * e);
        }
        ws[(pair*2+0)*256 + idx] = hp;
        ws[(pair*2+1)*256 + idx] = lp;
    } else if (T < 5696) {
        int i = T - 5632;
        ((float*)ws)[11264 + i] = W2[(i & 3) * 16 + (i >> 2)];
    }
}

// ---------------- main ----------------
// Block = 256 samples, 4 waves; wave owns 4 M-tiles (slots).
// tile(slot) = w + 4*(slot&1) + 8*(slot>>1); phase p stages rows [128p,128p+128)
// of one source flat into LDS; slots {2p,2p+1} consume it.
// Weight frags are read straight from global ws (L2/L3-resident, coalesced,
// zero reuse within a wave) -> LDS = 34.8 KB -> 4 blocks/CU.
__global__ __launch_bounds__(TPB, 4)
void nnue_main(const float* __restrict__ pov, const float* __restrict__ white,
               const float* __restrict__ black,
               const float* __restrict__ bwv, const float* __restrict__ bbv,
               const float* __restrict__ b0v, const float* __restrict__ b1v,
               const float* __restrict__ b2v,
               const u32* __restrict__ ws, float* __restrict__ out, int B)
{
    __shared__ __align__(16) u32 sBuf[8704];    // 34.8 KB: staging (6288) / act (4x2176)

    const int tid = threadIdx.x;
    if (tid < 16) sBuf[6272 + tid] = 0;         // pad so row-127 overreads see zeros

    const int w = tid >> 6, lane = tid & 63;
    const int n16 = lane & 15, kq = lane >> 4;
    const long long G = (long long)blockIdx.x * 256;
    const long long lastq = ((long long)B * 49) / 4 - 1;

    // FT accumulators [t][slot]
    f4 accw[2][4], accb[2][4];
    {
        float c0 = bwv[n16], c1 = bwv[16+n16];
        float d0 = bbv[n16], d1 = bbv[16+n16];
#pragma unroll
        for (int s = 0; s < 4; ++s) {
            accw[0][s] = {c0,c0,c0,c0}; accw[1][s] = {c1,c1,c1,c1};
            accb[0][s] = {d0,d0,d0,d0}; accb[1][s] = {d1,d1,d1,d1};
        }
    }

    const bf8* frag = (const bf8*)ws;           // global, L2-resident

#pragma unroll
    for (int p = 0; p < 2; ++p) {
#pragma unroll
        for (int src = 0; src < 2; ++src) {
            const float* sp_ = src ? black : white;
            __syncthreads();                    // prior phase reads complete
            {
                const long long q0 = ((G + 128 * p) * 49) >> 2;
                const f4* gp = (const f4*)sp_;
                for (int T = tid; T < 1568; T += TPB) {
                    long long qi = q0 + T;
                    if (qi > lastq) qi = lastq;
                    ((f4*)sBuf)[T] = gp[qi];
                }
            }
            __syncthreads();
#pragma unroll
            for (int ks2 = 0; ks2 < 2; ++ks2) {
                const int ks = src * 2 + ks2;
                bf8 Bh[2][2], Bl[2][2];
#pragma unroll
                for (int mat = 0; mat < 2; ++mat)
#pragma unroll
                    for (int t = 0; t < 2; ++t) {
                        int pair = (ks * 2 + mat) * 2 + t;
                        Bh[mat][t] = frag[(pair*2+0)*64 + lane];
                        Bl[mat][t] = frag[(pair*2+1)*64 + lane];
                    }
#pragma unroll
                for (int s = 0; s < 2; ++s) {
                    const int slot = 2 * p + s;
                    const int tile = w + 4 * s + 8 * p;
                    const int lr = tile * 16 + n16 - 128 * p;
                    const float* ap = (const float*)sBuf + lr * 49 + ks2 * 32 + kq * 8;
                    float a[8];
#pragma unroll
                    for (int j = 0; j < 8; ++j) a[j] = ap[j];
                    bf8 Ah, Al;
                    cvt_split8(a, Ah, Al);
#pragma unroll
                    for (int t = 0; t < 2; ++t) {
                        accw[t][slot] = mfma16(Ah, Bh[0][t], accw[t][slot]);
                        accw[t][slot] = mfma16(Al, Bh[0][t], accw[t][slot]);
                        accw[t][slot] = mfma16(Ah, Bl[0][t], accw[t][slot]);
                        accb[t][slot] = mfma16(Ah, Bh[1][t], accb[t][slot]);
                        accb[t][slot] = mfma16(Al, Bh[1][t], accb[t][slot]);
                        accb[t][slot] = mfma16(Ah, Bl[1][t], accb[t][slot]);
                    }
                }
            }
        }
    }

    __syncthreads();    // staging reads done; reuse sBuf as act scratch

    // blend + relu -> packed bf16 act rows [64][34] per wave
    u32* actB = sBuf + w * 2176;
#pragma unroll
    for (int slot = 0; slot < 4; ++slot) {
        const int tile = w + 4 * (slot & 1) + 8 * (slot >> 1);
#pragma unroll
        for (int r = 0; r < 4; ++r) {
            long long sp = G + tile * 16 + kq * 4 + r;
            if (sp > (long long)B - 1) sp = B - 1;
            float pvv = pov[sp];
            int row = slot * 16 + kq * 4 + r;
            float w0 = accw[0][slot][r], b0_ = accb[0][slot][r];
            float w1 = accw[1][slot][r], b1_ = accb[1][slot][r];
            float d0 = w0 - b0_, d1 = w1 - b1_;
            float e00 = fmaxf(fmaf(pvv, d0, b0_), 0.f);   // col n16
            float e01 = fmaxf(fmaf(pvv, d1, b1_), 0.f);   // col 16+n16
            float e10 = fmaxf(w0 - pvv * d0, 0.f);        // col 32+n16
            float e11 = fmaxf(w1 - pvv * d1, 0.f);        // col 48+n16
            actB[row * 34 + n16]      = bf16_rne(e00) | (bf16_rne(e01) << 16);
            actB[row * 34 + 16 + n16] = bf16_rne(e10) | (bf16_rne(e11) << 16);
        }
    }

    // L0: x0 = relu(base @ W0^T + b0)
    f4 acc0[2][4];
    {
        float c0 = b0v[n16], c1 = b0v[16+n16];
#pragma unroll
        for (int s = 0; s < 4; ++s) { acc0[0][s] = {c0,c0,c0,c0}; acc0[1][s] = {c1,c1,c1,c1}; }
    }
    __syncthreads();    // act rows visible to whole wave's reads
#pragma unroll
    for (int ks2 = 0; ks2 < 2; ++ks2) {
        bf8 Bh[2], Bl[2];
#pragma unroll
        for (int t = 0; t < 2; ++t) {
            int pair = 16 + ks2 * 2 + t;
            Bh[t] = frag[(pair*2+0)*64 + lane];
            Bl[t] = frag[(pair*2+1)*64 + lane];
        }
#pragma unroll
        for (int slot = 0; slot < 4; ++slot) {
            const u32* ap = actB + (slot * 16 + n16) * 34 + ks2 * 16 + kq * 4;
            u32x2 d01 = *(const u32x2*)ap;
            u32x2 d23 = *(const u32x2*)(ap + 2);
            u32x4 dv = {d01.x, d01.y, d23.x, d23.y};
            bf8 A = __builtin_bit_cast(bf8, dv);
#pragma unroll
            for (int t = 0; t < 2; ++t) {
                acc0[t][slot] = mfma16(A, Bh[t], acc0[t][slot]);
                acc0[t][slot] = mfma16(A, Bl[t], acc0[t][slot]);
            }
        }
    }
    // relu; restage x0 (packed) for L1
#pragma unroll
    for (int slot = 0; slot < 4; ++slot)
#pragma unroll
        for (int r = 0; r < 4; ++r) {
            float v0 = fmaxf(acc0[0][slot][r], 0.f);
            float v1 = fmaxf(acc0[1][slot][r], 0.f);
            acc0[0][slot][r] = v0; acc0[1][slot][r] = v1;
            actB[(slot * 16 + kq * 4 + r) * 34 + n16] = bf16_rne(v0) | (bf16_rne(v1) << 16);
        }

    // L1: x1 = x0 @ W1^T + b1
    f4 acc1[2][4];
    {
        float c0 = b1v[n16], c1 = b1v[16+n16];
#pragma unroll
        for (int s = 0; s < 4; ++s) { acc1[0][s] = {c0,c0,c0,c0}; acc1[1][s] = {c1,c1,c1,c1}; }
    }
    {
        bf8 Bh[2], Bl[2];
#pragma unroll
        for (int t = 0; t < 2; ++t) {
            int pair = 20 + t;
            Bh[t] = frag[(pair*2+0)*64 + lane];
            Bl[t] = frag[(pair*2+1)*64 + lane];
        }
#pragma unroll
        for (int slot = 0; slot < 4; ++slot) {
            const u32* ap = actB + (slot * 16 + n16) * 34 + kq * 4;
            u32x2 d01 = *(const u32x2*)ap;
            u32x2 d23 = *(const u32x2*)(ap + 2);
            u32x4 dv = {d01.x, d01.y, d23.x, d23.y};
            bf8 A = __builtin_bit_cast(bf8, dv);
#pragma unroll
            for (int t = 0; t < 2; ++t) {
                acc1[t][slot] = mfma16(A, Bh[t], acc1[t][slot]);
                acc1[t][slot] = mfma16(A, Bl[t], acc1[t][slot]);
            }
        }
    }

    // out = x0.W2[0:32] + relu(x1).W2[32:64] + b2
    f4 w2 = *(const f4*)&((const float*)ws)[11264 + n16 * 4];
    float b2s = b2v[0];
#pragma unroll
    for (int slot = 0; slot < 4; ++slot) {
        const int tile = w + 4 * (slot & 1) + 8 * (slot >> 1);
#pragma unroll
        for (int r = 0; r < 4; ++r) {
            float v = acc0[0][slot][r] * w2.x + acc0[1][slot][r] * w2.y
                    + fmaxf(acc1[0][slot][r], 0.f) * w2.z
                    + fmaxf(acc1[1][slot][r], 0.f) * w2.w;
            v += __shfl_xor(v, 1);
            v += __shfl_xor(v, 2);
            v += __shfl_xor(v, 4);
            v += __shfl_xor(v, 8);
            long long so = G + tile * 16 + kq * 4 + r;
            if (n16 == 0 && so < B) out[so] = v + b2s;
        }
    }
}

extern "C" void kernel_launch(void* const* d_in, const int* in_sizes, int n_in,
                              void* d_out, int out_size, void* d_ws, size_t ws_size,
                              hipStream_t stream)
{
    const float* pov   = (const float*)d_in[0];
    const float* white = (const float*)d_in[1];
    const float* black = (const float*)d_in[2];
    const float* Ww = (const float*)d_in[3];
    const float* bw = (const float*)d_in[4];
    const float* Wb = (const float*)d_in[5];
    const float* bb = (const float*)d_in[6];
    const float* W0 = (const float*)d_in[7];
    const float* b0 = (const float*)d_in[8];
    const float* W1 = (const float*)d_in[9];
    const float* b1 = (const float*)d_in[10];
    const float* W2 = (const float*)d_in[11];
    const float* b2 = (const float*)d_in[12];
    float* out = (float*)d_out;

    const int B = in_sizes[0];
    u32* ws = (u32*)d_ws;

    hipLaunchKernelGGL(nnue_prep, dim3(23), dim3(256), 0, stream,
                       Ww, Wb, W0, W1, W2, ws);
    hipLaunchKernelGGL(nnue_main, dim3((B + 255) / 256), dim3(TPB), 0, stream,
                       pov, white, black, bw, bb, b0, b1, b2, ws, out, B);
}